// Round 8
// baseline (119.231 us; speedup 1.0000x reference)
//
#include <hip/hip_runtime.h>

#define N_NODES 100000
#define N_EDGES 1600000
#define D 32
#define Q8 256.0f          // fixed-point scale 2^8
#define INV_Q8 (1.0f / 256.0f)
#define ROWS_PER_BLOCK 64
#define XS_STRIDE 36       // floats; 16B-aligned, proven bank-safe (R0)
#define NTILES ((N_NODES + ROWS_PER_BLOCK - 1) / ROWS_PER_BLOCK)  // 1563
#define POISON64 0xAAAAAAAAAAAAAAAAULL
#define POISON32 0xAAAAAAAAu

// ---- bucket pipeline geometry ----
#define BKT_NODES 256                    // nodes per bucket (dst >> 8)
#define NB ((N_NODES + BKT_NODES - 1) / BKT_NODES)   // 391
#define CAPB 8192                        // global words per bucket
#define EPB 4096                         // edges per K1 block
#define K1_EPT (EPB / 256)               // 16
#define K1_BLOCKS ((N_EDGES + EPB - 1) / EPB)        // 391
#define K2_THREADS 1024                  // R8: 512->1024, 2x waves/CU for
                                         // gather latency hiding
#define SORT_CAP 6144                    // LDS sort capacity (mean 4096, sd 64)
#define MAX_WPT 6                        // SORT_CAP / K2_THREADS

// ---- workspace layout (19.3 MB) ----
// gcur : [NB] u32        @ 0     (poisoned; counts mod 2^32)
// buf  : [NB][CAPB] u32  @ 4096  edge words: src(17b) | doff(8b)<<17
// ypk  : [N_NODES][8] u64 @ BUF_OFF+12.8MB   packed q8 of y = x @ W^T
#define GCUR_OFF 0
#define BUF_OFF  4096
#define YPK_OFF  (BUF_OFF + (size_t)NB * CAPB * 4)
#define WS_NEEDED (YPK_OFF + (size_t)N_NODES * 8 * 8)

// Decode one u64 packed sum into 4 floats (signed 16-bit lanes with borrow).
__device__ __forceinline__ void decode4(unsigned long long s, float* o) {
    short v0 = (short)(s & 0xFFFF);
    s = (s >> 16) + (unsigned long long)(v0 < 0 ? 1 : 0);
    short v1 = (short)(s & 0xFFFF);
    s = (s >> 16) + (unsigned long long)(v1 < 0 ? 1 : 0);
    short v2 = (short)(s & 0xFFFF);
    s = (s >> 16) + (unsigned long long)(v2 < 0 ? 1 : 0);
    short v3 = (short)(s & 0xFFFF);
    o[0] = (float)v0 * INV_Q8;
    o[1] = (float)v1 * INV_Q8;
    o[2] = (float)v2 * INV_Q8;
    o[3] = (float)v3 * INV_Q8;
}

// Fused K0+K1 (R7-proven, unchanged).
// Blocks [0, NTILES):           pack  y = x @ W^T -> ypk
// Blocks [NTILES, +K1_BLOCKS):  bucket-scatter edges
__global__ __launch_bounds__(256) void gcn_pack_bucket_kernel(
    const float4* __restrict__ x4,          // x as [N_NODES][8] float4
    const float* __restrict__ W,
    const int* __restrict__ src,
    const int* __restrict__ dst,
    unsigned long long* __restrict__ ypk,   // [N_NODES][8] u64
    unsigned int* __restrict__ gcur,        // [NB] poisoned u32
    unsigned int* __restrict__ buf) {       // [NB][CAPB]
    __shared__ float xs[ROWS_PER_BLOCK * XS_STRIDE];
    __shared__ float Wt[D * D];
    __shared__ unsigned int cnt[NB];
    __shared__ unsigned int base[NB];
    int t = threadIdx.x;
    int b = blockIdx.x;

    if (b < NTILES) {
        // ---------------- pack: y = x @ W^T, quantize Q8, pack 4x16b/u64 ---
#pragma unroll
        for (int i = t; i < D * D; i += 256) {
            int o = i >> 5, k = i & 31;
            Wt[k * D + o] = W[i];
        }
        int row0 = b * ROWS_PER_BLOCK;
        int r = t >> 2;
        int c = t & 3;
        int grow = row0 + r;
        if (grow < N_NODES) {
            float4 v0 = x4[(size_t)grow * 8 + c * 2];
            float4 v1 = x4[(size_t)grow * 8 + c * 2 + 1];
            float* dp = &xs[r * XS_STRIDE + c * 8];
            dp[0] = v0.x; dp[1] = v0.y; dp[2] = v0.z; dp[3] = v0.w;
            dp[4] = v1.x; dp[5] = v1.y; dp[6] = v1.z; dp[7] = v1.w;
        }
        __syncthreads();
        if (grow >= N_NODES) return;

        int q = t & 3;
        float acc[8];
#pragma unroll
        for (int j = 0; j < 8; ++j) acc[j] = 0.f;
#pragma unroll
        for (int k = 0; k < D; ++k) {
            float v = xs[r * XS_STRIDE + k];
#pragma unroll
            for (int j = 0; j < 8; ++j) acc[j] += v * Wt[k * D + q * 8 + j];
        }
        long long a[8];
#pragma unroll
        for (int j = 0; j < 8; ++j)
            a[j] = (long long)__float2int_rn(acc[j] * Q8);
        unsigned long long p0 = (unsigned long long)(
            a[0] + (a[1] << 16) + (a[2] << 32) + (a[3] << 48));
        unsigned long long p1 = (unsigned long long)(
            a[4] + (a[5] << 16) + (a[6] << 32) + (a[7] << 48));
        ulonglong2* op = (ulonglong2*)(ypk + (size_t)grow * 8 + q * 2);
        *op = make_ulonglong2(p0, p1);
        return;
    }

    // ---------------- bucket-scatter (R4-proven) ------------------------
    for (int j = t; j < NB; j += 256) cnt[j] = 0;
    __syncthreads();

    int e0 = (b - NTILES) * EPB;
    int s[K1_EPT], bkt[K1_EPT];
    unsigned int rank[K1_EPT], word[K1_EPT];
    bool ok[K1_EPT];
#pragma unroll
    for (int i = 0; i < K1_EPT; ++i) {
        int e = e0 + i * 256 + t;
        ok[i] = e < N_EDGES;
        int dd = 0;
        if (ok[i]) { s[i] = src[e]; dd = dst[e]; }
        bkt[i] = dd >> 8;
        word[i] = (unsigned int)s[i] | ((unsigned int)(dd & 255) << 17);
    }
#pragma unroll
    for (int i = 0; i < K1_EPT; ++i)
        if (ok[i]) rank[i] = atomicAdd(&cnt[bkt[i]], 1u);  // LDS on-chip
    __syncthreads();

    for (int j = t; j < NB; j += 256) {
        unsigned int c = cnt[j];
        base[j] = c ? (atomicAdd(&gcur[j], c) - POISON32) : 0u;
    }
    __syncthreads();

#pragma unroll
    for (int i = 0; i < K1_EPT; ++i) {
        if (ok[i]) {
            unsigned int idx = base[bkt[i]] + rank[i];
            if (idx < CAPB)
                buf[(size_t)bkt[i] * CAPB + idx] = word[i];
        }
    }
}

// K2: in-LDS counting sort by doff, then ATOMIC-FREE register gather-sum.
// R8 changes vs R7 (which measured ~32 us, latency-bound):
//  - 1024 threads/block: 16 waves/block -> ~24 waves/CU (was 12) for TLP
//  - gather ILP 8 (was 4): deg~16 -> 2 dependent batches/node (was 4)
__global__ __launch_bounds__(K2_THREADS) void gcn_sort_agg_kernel(
    const unsigned int* __restrict__ gcur,
    const unsigned int* __restrict__ buf,
    const unsigned long long* __restrict__ ypk,
    float* __restrict__ out) {
    __shared__ unsigned int sorted[SORT_CAP];     // 24 KB
    __shared__ unsigned int cnt[BKT_NODES];       // 1 KB
    __shared__ unsigned int pfx[BKT_NODES + 1];
    __shared__ unsigned int gsum[8];
    int t = threadIdx.x;
    int b = blockIdx.x;

    for (int j = t; j < BKT_NODES; j += K2_THREADS) cnt[j] = 0;
    __syncthreads();

    unsigned int cntb = gcur[b] - POISON32;
    if (cntb > SORT_CAP) cntb = SORT_CAP;         // 32-sigma; never clamps
    const unsigned int* bb = buf + (size_t)b * CAPB;

    // stage words in registers (fixed-bound unroll: no scratch, rule #20)
    unsigned int w[MAX_WPT], rk[MAX_WPT];
    bool ok[MAX_WPT];
#pragma unroll
    for (int i = 0; i < MAX_WPT; ++i) {
        unsigned int g = (unsigned int)t + (unsigned int)i * K2_THREADS;
        ok[i] = g < cntb;
        w[i] = ok[i] ? bb[g] : 0u;
    }
#pragma unroll
    for (int i = 0; i < MAX_WPT; ++i)
        if (ok[i]) rk[i] = atomicAdd(&cnt[w[i] >> 17], 1u);  // rank atomics
    __syncthreads();

    // two-level exclusive prefix over 256 counts
    if (t < 8) {
        unsigned int s = 0;
#pragma unroll
        for (int j = 0; j < 32; ++j) s += cnt[t * 32 + j];
        gsum[t] = s;
    }
    __syncthreads();
    if (t == 0) {
        unsigned int s = 0;
#pragma unroll
        for (int g = 0; g < 8; ++g) {
            unsigned int v = gsum[g]; gsum[g] = s; s += v;
        }
        pfx[BKT_NODES] = s;
    }
    __syncthreads();
    if (t < BKT_NODES) {
        unsigned int s = gsum[t >> 5];
        int g0 = (t >> 5) << 5;
        for (int j = g0; j < t; ++j) s += cnt[j];
        pfx[t] = s;
    }
    __syncthreads();

    // scatter into dst-sorted order
#pragma unroll
    for (int i = 0; i < MAX_WPT; ++i)
        if (ok[i]) sorted[pfx[w[i] >> 17] + rk[i]] = w[i];
    __syncthreads();

    // register gather-sum: thread = (node, f4), 2 passes cover 256 nodes.
    // Lanes t&7 of one node read consecutive u64s -> one 64B line per edge.
    int node0 = b << 8;
    int f4 = t & 7;
#pragma unroll
    for (int p = 0; p < 2; ++p) {
        int r = p * 128 + (t >> 3);
        unsigned int beg = pfx[r];
        unsigned int end = pfx[r + 1];
        unsigned long long sum = 0;
        unsigned int k = beg;
        for (; k + 8 <= end; k += 8) {        // 8 loads in flight
            unsigned int w0 = sorted[k],     w1 = sorted[k + 1];
            unsigned int w2 = sorted[k + 2], w3 = sorted[k + 3];
            unsigned int w4 = sorted[k + 4], w5 = sorted[k + 5];
            unsigned int w6 = sorted[k + 6], w7 = sorted[k + 7];
            unsigned long long y0 = ypk[(size_t)(w0 & 0x1FFFF) * 8 + f4];
            unsigned long long y1 = ypk[(size_t)(w1 & 0x1FFFF) * 8 + f4];
            unsigned long long y2 = ypk[(size_t)(w2 & 0x1FFFF) * 8 + f4];
            unsigned long long y3 = ypk[(size_t)(w3 & 0x1FFFF) * 8 + f4];
            unsigned long long y4 = ypk[(size_t)(w4 & 0x1FFFF) * 8 + f4];
            unsigned long long y5 = ypk[(size_t)(w5 & 0x1FFFF) * 8 + f4];
            unsigned long long y6 = ypk[(size_t)(w6 & 0x1FFFF) * 8 + f4];
            unsigned long long y7 = ypk[(size_t)(w7 & 0x1FFFF) * 8 + f4];
            sum += (y0 + y1) + (y2 + y3) + ((y4 + y5) + (y6 + y7));
        }
        for (; k < end; ++k)
            sum += ypk[(size_t)(sorted[k] & 0x1FFFF) * 8 + f4];
        int grow = node0 + r;
        if (grow < N_NODES) {
            float o4[4];
            decode4(sum, o4);
            *(float4*)(out + (size_t)grow * D + f4 * 4) =
                make_float4(o4[0], o4[1], o4[2], o4[3]);
        }
    }
}

// ---------------- fallback path (proven round-0): atomic scatter + matmul ----

__global__ __launch_bounds__(256) void gcn_scatter_q_kernel(
    const int* __restrict__ src,
    const int* __restrict__ dst,
    const float4* __restrict__ x4,
    unsigned long long* __restrict__ agg) {
    int gid = blockIdx.x * 256 + threadIdx.x;
    int e = gid >> 3;
    int f4 = gid & 7;
    if (e >= N_EDGES) return;
    int s = src[e];
    int dd = dst[e];
    float4 v = x4[(size_t)s * 8 + f4];
    long long a0 = (long long)__float2int_rn(v.x * Q8);
    long long a1 = (long long)__float2int_rn(v.y * Q8);
    long long a2 = (long long)__float2int_rn(v.z * Q8);
    long long a3 = (long long)__float2int_rn(v.w * Q8);
    unsigned long long p =
        (unsigned long long)(a0 + (a1 << 16) + (a2 << 32) + (a3 << 48));
    atomicAdd(&agg[(size_t)dd * 8 + f4], p);
}

__global__ __launch_bounds__(256) void gcn_matmul_kernel(
    const unsigned long long* __restrict__ agg,
    const float* __restrict__ W,
    float* __restrict__ out) {
    __shared__ float xs[ROWS_PER_BLOCK * XS_STRIDE];
    __shared__ float Wt[D * D];
    int t = threadIdx.x;
    int b = blockIdx.x;

#pragma unroll
    for (int i = t; i < D * D; i += 256) {
        int o = i >> 5, k = i & 31;
        Wt[k * D + o] = W[i];
    }

    int row0 = b * ROWS_PER_BLOCK;
    {
        int r = t >> 2;
        int c = t & 3;
        int grow = row0 + r;
        if (grow < N_NODES) {
            const unsigned long long* rp = agg + (size_t)grow * 8 + c * 2;
            unsigned long long s0 = rp[0] - POISON64;
            unsigned long long s1 = rp[1] - POISON64;
            float* dstp = &xs[r * XS_STRIDE + c * 8];
            decode4(s0, dstp);
            decode4(s1, dstp + 4);
        }
    }
    __syncthreads();

    int r = t >> 2;
    int q = t & 3;
    int grow = row0 + r;
    if (grow >= N_NODES) return;

    float acc8[8];
#pragma unroll
    for (int j = 0; j < 8; ++j) acc8[j] = 0.f;
#pragma unroll
    for (int k = 0; k < D; ++k) {
        float v = xs[r * XS_STRIDE + k];
#pragma unroll
        for (int j = 0; j < 8; ++j) acc8[j] += v * Wt[k * D + q * 8 + j];
    }
    float4* op = (float4*)(out + (size_t)grow * D + q * 8);
    op[0] = make_float4(acc8[0], acc8[1], acc8[2], acc8[3]);
    op[1] = make_float4(acc8[4], acc8[5], acc8[6], acc8[7]);
}

extern "C" void kernel_launch(void* const* d_in, const int* in_sizes, int n_in,
                              void* d_out, int out_size, void* d_ws, size_t ws_size,
                              hipStream_t stream) {
    const float* x = (const float*)d_in[0];
    const int* edge_index = (const int*)d_in[1];  // [2, N_EDGES] int32
    const float* W = (const float*)d_in[2];
    float* out = (float*)d_out;

    const int* src = edge_index;
    const int* dst = edge_index + N_EDGES;

    char* ws = (char*)d_ws;  // poisoned 0xAA each iteration

    if (ws_size >= WS_NEEDED) {
        unsigned int* gcur = (unsigned int*)(ws + GCUR_OFF);
        unsigned int* buf = (unsigned int*)(ws + BUF_OFF);
        unsigned long long* ypk = (unsigned long long*)(ws + YPK_OFF);

        // fused pack (VALU-bound) + bucket-scatter (atomic/BW-bound)
        gcn_pack_bucket_kernel<<<NTILES + K1_BLOCKS, 256, 0, stream>>>(
            (const float4*)x, W, src, dst, ypk, gcur, buf);
        // counting-sort + atomic-free register gather-sum
        gcn_sort_agg_kernel<<<NB, K2_THREADS, 0, stream>>>(
            gcur, buf, ypk, out);
    } else {
        // proven round-0 path
        unsigned long long* agg = (unsigned long long*)ws;
        gcn_scatter_q_kernel<<<(N_EDGES * 8) / 256, 256, 0, stream>>>(
            src, dst, (const float4*)x, agg);
        gcn_matmul_kernel<<<NTILES, 256, 0, stream>>>(agg, W, out);
    }
}

// Round 9
// 118.270 us; speedup vs baseline: 1.0081x; 1.0081x over previous
//
#include <hip/hip_runtime.h>

#define N_NODES 100000
#define N_EDGES 1600000
#define D 32
#define Q8 256.0f          // fixed-point scale 2^8
#define INV_Q8 (1.0f / 256.0f)
#define ROWS_PER_BLOCK 64
#define XS_STRIDE 36       // floats; 16B-aligned, proven bank-safe (R0)
#define NTILES ((N_NODES + ROWS_PER_BLOCK - 1) / ROWS_PER_BLOCK)  // 1563
#define POISON64 0xAAAAAAAAAAAAAAAAULL
#define POISON32 0xAAAAAAAAu

// ---- bucket pipeline geometry ----
#define BKT_NODES 256                    // nodes per bucket (dst >> 8)
#define NB ((N_NODES + BKT_NODES - 1) / BKT_NODES)   // 391
#define CAPB 8192                        // global words per bucket
#define EPB 4096                         // edges per K1 block
#define K1_EPT (EPB / 256)               // 16
#define K1_BLOCKS ((N_EDGES + EPB - 1) / EPB)        // 391
// K2 (R9): 4 quarter-blocks per bucket -> 1564 blocks (~6/CU grid fill),
// each sorts+gathers a 64-node slice: ~4x shorter serial sort chain.
#define K2_THREADS 512
#define QCAP 2048                        // words per quarter (mean 1024, sd 32)
#define MAX_WPT 12                       // bucket stage: 6144 / 512

// ---- workspace layout (19.3 MB) ----
// gcur : [NB] u32        @ 0     (poisoned; counts mod 2^32)
// buf  : [NB][CAPB] u32  @ 4096  edge words: src(17b) | doff(8b)<<17
// ypk  : [N_NODES][8] u64 @ BUF_OFF+12.8MB   packed q8 of y = x @ W^T
#define GCUR_OFF 0
#define BUF_OFF  4096
#define YPK_OFF  (BUF_OFF + (size_t)NB * CAPB * 4)
#define WS_NEEDED (YPK_OFF + (size_t)N_NODES * 8 * 8)

// Decode one u64 packed sum into 4 floats (signed 16-bit lanes with borrow).
__device__ __forceinline__ void decode4(unsigned long long s, float* o) {
    short v0 = (short)(s & 0xFFFF);
    s = (s >> 16) + (unsigned long long)(v0 < 0 ? 1 : 0);
    short v1 = (short)(s & 0xFFFF);
    s = (s >> 16) + (unsigned long long)(v1 < 0 ? 1 : 0);
    short v2 = (short)(s & 0xFFFF);
    s = (s >> 16) + (unsigned long long)(v2 < 0 ? 1 : 0);
    short v3 = (short)(s & 0xFFFF);
    o[0] = (float)v0 * INV_Q8;
    o[1] = (float)v1 * INV_Q8;
    o[2] = (float)v2 * INV_Q8;
    o[3] = (float)v3 * INV_Q8;
}

// Fused K0+K1 (R7-proven, unchanged).
// Blocks [0, NTILES):           pack  y = x @ W^T -> ypk
// Blocks [NTILES, +K1_BLOCKS):  bucket-scatter edges
__global__ __launch_bounds__(256) void gcn_pack_bucket_kernel(
    const float4* __restrict__ x4,          // x as [N_NODES][8] float4
    const float* __restrict__ W,
    const int* __restrict__ src,
    const int* __restrict__ dst,
    unsigned long long* __restrict__ ypk,   // [N_NODES][8] u64
    unsigned int* __restrict__ gcur,        // [NB] poisoned u32
    unsigned int* __restrict__ buf) {       // [NB][CAPB]
    __shared__ float xs[ROWS_PER_BLOCK * XS_STRIDE];
    __shared__ float Wt[D * D];
    __shared__ unsigned int cnt[NB];
    __shared__ unsigned int base[NB];
    int t = threadIdx.x;
    int b = blockIdx.x;

    if (b < NTILES) {
        // ---------------- pack: y = x @ W^T, quantize Q8, pack 4x16b/u64 ---
#pragma unroll
        for (int i = t; i < D * D; i += 256) {
            int o = i >> 5, k = i & 31;
            Wt[k * D + o] = W[i];
        }
        int row0 = b * ROWS_PER_BLOCK;
        int r = t >> 2;
        int c = t & 3;
        int grow = row0 + r;
        if (grow < N_NODES) {
            float4 v0 = x4[(size_t)grow * 8 + c * 2];
            float4 v1 = x4[(size_t)grow * 8 + c * 2 + 1];
            float* dp = &xs[r * XS_STRIDE + c * 8];
            dp[0] = v0.x; dp[1] = v0.y; dp[2] = v0.z; dp[3] = v0.w;
            dp[4] = v1.x; dp[5] = v1.y; dp[6] = v1.z; dp[7] = v1.w;
        }
        __syncthreads();
        if (grow >= N_NODES) return;

        int q = t & 3;
        float acc[8];
#pragma unroll
        for (int j = 0; j < 8; ++j) acc[j] = 0.f;
#pragma unroll
        for (int k = 0; k < D; ++k) {
            float v = xs[r * XS_STRIDE + k];
#pragma unroll
            for (int j = 0; j < 8; ++j) acc[j] += v * Wt[k * D + q * 8 + j];
        }
        long long a[8];
#pragma unroll
        for (int j = 0; j < 8; ++j)
            a[j] = (long long)__float2int_rn(acc[j] * Q8);
        unsigned long long p0 = (unsigned long long)(
            a[0] + (a[1] << 16) + (a[2] << 32) + (a[3] << 48));
        unsigned long long p1 = (unsigned long long)(
            a[4] + (a[5] << 16) + (a[6] << 32) + (a[7] << 48));
        ulonglong2* op = (ulonglong2*)(ypk + (size_t)grow * 8 + q * 2);
        *op = make_ulonglong2(p0, p1);
        return;
    }

    // ---------------- bucket-scatter (R4-proven) ------------------------
    for (int j = t; j < NB; j += 256) cnt[j] = 0;
    __syncthreads();

    int e0 = (b - NTILES) * EPB;
    int s[K1_EPT], bkt[K1_EPT];
    unsigned int rank[K1_EPT], word[K1_EPT];
    bool ok[K1_EPT];
#pragma unroll
    for (int i = 0; i < K1_EPT; ++i) {
        int e = e0 + i * 256 + t;
        ok[i] = e < N_EDGES;
        int dd = 0;
        if (ok[i]) { s[i] = src[e]; dd = dst[e]; }
        bkt[i] = dd >> 8;
        word[i] = (unsigned int)s[i] | ((unsigned int)(dd & 255) << 17);
    }
#pragma unroll
    for (int i = 0; i < K1_EPT; ++i)
        if (ok[i]) rank[i] = atomicAdd(&cnt[bkt[i]], 1u);  // LDS on-chip
    __syncthreads();

    for (int j = t; j < NB; j += 256) {
        unsigned int c = cnt[j];
        base[j] = c ? (atomicAdd(&gcur[j], c) - POISON32) : 0u;
    }
    __syncthreads();

#pragma unroll
    for (int i = 0; i < K1_EPT; ++i) {
        if (ok[i]) {
            unsigned int idx = base[bkt[i]] + rank[i];
            if (idx < CAPB)
                buf[(size_t)bkt[i] * CAPB + idx] = word[i];
        }
    }
}

// K2 (R9): quarter-bucket sort + atomic-free register gather-sum.
// Each block owns 64 nodes (quarter q of bucket b>>2): filters the bucket's
// words on 2 doff bits, rank-atomics ~1024 words into cnt[64] (4x fewer
// same-address collisions than the 256-node sort), 1-wave shfl prefix,
// scatter, then a single-pass gather (8 threads/node x 64 nodes).
// Grid 1564 blocks (~6/CU) amortizes the serial sort prologue and the tail.
__global__ __launch_bounds__(K2_THREADS) void gcn_sort_agg_kernel(
    const unsigned int* __restrict__ gcur,
    const unsigned int* __restrict__ buf,
    const unsigned long long* __restrict__ ypk,
    float* __restrict__ out) {
    __shared__ unsigned int sorted[QCAP];         // 8 KB
    __shared__ unsigned int cnt[64];
    __shared__ unsigned int pfx[65];
    int t = threadIdx.x;
    int bq = blockIdx.x;
    int b = bq >> 2;                  // bucket
    int q = bq & 3;                   // 64-node quarter within bucket

    if (t < 64) cnt[t] = 0;
    __syncthreads();

    unsigned int cntb = gcur[b] - POISON32;
    if (cntb > 6144u) cntb = 6144u;               // 32-sigma; never clamps
    const unsigned int* bb = buf + (size_t)b * CAPB;

    // stage + filter (fixed-bound unroll: no scratch, rule #20)
    unsigned int w[MAX_WPT], rk[MAX_WPT];
    bool ok[MAX_WPT];
#pragma unroll
    for (int i = 0; i < MAX_WPT; ++i) {
        unsigned int g = (unsigned int)t + (unsigned int)i * K2_THREADS;
        ok[i] = (g < cntb);
        w[i] = ok[i] ? bb[g] : 0u;
        ok[i] = ok[i] && (((w[i] >> 23) & 3u) == (unsigned int)q);
    }
#pragma unroll
    for (int i = 0; i < MAX_WPT; ++i)
        if (ok[i]) rk[i] = atomicAdd(&cnt[(w[i] >> 17) & 63u], 1u);
    __syncthreads();

    // exclusive prefix over 64 counts: one wave, shfl scan
    if (t < 64) {
        unsigned int c = cnt[t];
        unsigned int v = c;
#pragma unroll
        for (int off = 1; off < 64; off <<= 1) {
            unsigned int u = __shfl_up(v, off, 64);
            if (t >= off) v += u;
        }
        pfx[t] = v - c;               // exclusive
        if (t == 63) pfx[64] = v;     // total
    }
    __syncthreads();

    // scatter into dst-sorted order (bounded: per-quarter total <= QCAP)
#pragma unroll
    for (int i = 0; i < MAX_WPT; ++i) {
        if (ok[i]) {
            unsigned int idx = pfx[(w[i] >> 17) & 63u] + rk[i];
            if (idx < QCAP) sorted[idx] = w[i];
        }
    }
    __syncthreads();

    // register gather-sum: thread = (node, f4), single pass (512 = 64*8).
    // Lanes t&7 of one node read consecutive u64s -> one 64B line per edge.
    int r = t >> 3;                   // node within quarter
    int f4 = t & 7;
    unsigned int beg = pfx[r];
    unsigned int end = pfx[r + 1];
    unsigned long long sum = 0;
    unsigned int k = beg;
    for (; k + 8 <= end; k += 8) {    // 8 loads in flight
        unsigned int w0 = sorted[k],     w1 = sorted[k + 1];
        unsigned int w2 = sorted[k + 2], w3 = sorted[k + 3];
        unsigned int w4 = sorted[k + 4], w5 = sorted[k + 5];
        unsigned int w6 = sorted[k + 6], w7 = sorted[k + 7];
        unsigned long long y0 = ypk[(size_t)(w0 & 0x1FFFF) * 8 + f4];
        unsigned long long y1 = ypk[(size_t)(w1 & 0x1FFFF) * 8 + f4];
        unsigned long long y2 = ypk[(size_t)(w2 & 0x1FFFF) * 8 + f4];
        unsigned long long y3 = ypk[(size_t)(w3 & 0x1FFFF) * 8 + f4];
        unsigned long long y4 = ypk[(size_t)(w4 & 0x1FFFF) * 8 + f4];
        unsigned long long y5 = ypk[(size_t)(w5 & 0x1FFFF) * 8 + f4];
        unsigned long long y6 = ypk[(size_t)(w6 & 0x1FFFF) * 8 + f4];
        unsigned long long y7 = ypk[(size_t)(w7 & 0x1FFFF) * 8 + f4];
        sum += (y0 + y1) + (y2 + y3) + ((y4 + y5) + (y6 + y7));
    }
    for (; k < end; ++k)
        sum += ypk[(size_t)(sorted[k] & 0x1FFFF) * 8 + f4];

    int grow = (b << 8) + (q << 6) + r;
    if (grow < N_NODES) {
        float o4[4];
        decode4(sum, o4);
        *(float4*)(out + (size_t)grow * D + f4 * 4) =
            make_float4(o4[0], o4[1], o4[2], o4[3]);
    }
}

// ---------------- fallback path (proven round-0): atomic scatter + matmul ----

__global__ __launch_bounds__(256) void gcn_scatter_q_kernel(
    const int* __restrict__ src,
    const int* __restrict__ dst,
    const float4* __restrict__ x4,
    unsigned long long* __restrict__ agg) {
    int gid = blockIdx.x * 256 + threadIdx.x;
    int e = gid >> 3;
    int f4 = gid & 7;
    if (e >= N_EDGES) return;
    int s = src[e];
    int dd = dst[e];
    float4 v = x4[(size_t)s * 8 + f4];
    long long a0 = (long long)__float2int_rn(v.x * Q8);
    long long a1 = (long long)__float2int_rn(v.y * Q8);
    long long a2 = (long long)__float2int_rn(v.z * Q8);
    long long a3 = (long long)__float2int_rn(v.w * Q8);
    unsigned long long p =
        (unsigned long long)(a0 + (a1 << 16) + (a2 << 32) + (a3 << 48));
    atomicAdd(&agg[(size_t)dd * 8 + f4], p);
}

__global__ __launch_bounds__(256) void gcn_matmul_kernel(
    const unsigned long long* __restrict__ agg,
    const float* __restrict__ W,
    float* __restrict__ out) {
    __shared__ float xs[ROWS_PER_BLOCK * XS_STRIDE];
    __shared__ float Wt[D * D];
    int t = threadIdx.x;
    int b = blockIdx.x;

#pragma unroll
    for (int i = t; i < D * D; i += 256) {
        int o = i >> 5, k = i & 31;
        Wt[k * D + o] = W[i];
    }

    int row0 = b * ROWS_PER_BLOCK;
    {
        int r = t >> 2;
        int c = t & 3;
        int grow = row0 + r;
        if (grow < N_NODES) {
            const unsigned long long* rp = agg + (size_t)grow * 8 + c * 2;
            unsigned long long s0 = rp[0] - POISON64;
            unsigned long long s1 = rp[1] - POISON64;
            float* dstp = &xs[r * XS_STRIDE + c * 8];
            decode4(s0, dstp);
            decode4(s1, dstp + 4);
        }
    }
    __syncthreads();

    int r = t >> 2;
    int q = t & 3;
    int grow = row0 + r;
    if (grow >= N_NODES) return;

    float acc8[8];
#pragma unroll
    for (int j = 0; j < 8; ++j) acc8[j] = 0.f;
#pragma unroll
    for (int k = 0; k < D; ++k) {
        float v = xs[r * XS_STRIDE + k];
#pragma unroll
        for (int j = 0; j < 8; ++j) acc8[j] += v * Wt[k * D + q * 8 + j];
    }
    float4* op = (float4*)(out + (size_t)grow * D + q * 8);
    op[0] = make_float4(acc8[0], acc8[1], acc8[2], acc8[3]);
    op[1] = make_float4(acc8[4], acc8[5], acc8[6], acc8[7]);
}

extern "C" void kernel_launch(void* const* d_in, const int* in_sizes, int n_in,
                              void* d_out, int out_size, void* d_ws, size_t ws_size,
                              hipStream_t stream) {
    const float* x = (const float*)d_in[0];
    const int* edge_index = (const int*)d_in[1];  // [2, N_EDGES] int32
    const float* W = (const float*)d_in[2];
    float* out = (float*)d_out;

    const int* src = edge_index;
    const int* dst = edge_index + N_EDGES;

    char* ws = (char*)d_ws;  // poisoned 0xAA each iteration

    if (ws_size >= WS_NEEDED) {
        unsigned int* gcur = (unsigned int*)(ws + GCUR_OFF);
        unsigned int* buf = (unsigned int*)(ws + BUF_OFF);
        unsigned long long* ypk = (unsigned long long*)(ws + YPK_OFF);

        // fused pack (VALU-bound) + bucket-scatter (atomic/BW-bound)
        gcn_pack_bucket_kernel<<<NTILES + K1_BLOCKS, 256, 0, stream>>>(
            (const float4*)x, W, src, dst, ypk, gcur, buf);
        // quarter-bucket counting-sort + atomic-free register gather-sum
        gcn_sort_agg_kernel<<<NB * 4, K2_THREADS, 0, stream>>>(
            gcur, buf, ypk, out);
    } else {
        // proven round-0 path
        unsigned long long* agg = (unsigned long long*)ws;
        gcn_scatter_q_kernel<<<(N_EDGES * 8) / 256, 256, 0, stream>>>(
            src, dst, (const float4*)x, agg);
        gcn_matmul_kernel<<<NTILES, 256, 0, stream>>>(agg, W, out);
    }
}